// Round 6
// baseline (119.386 us; speedup 1.0000x reference)
//
#include <hip/hip_runtime.h>

typedef float f32x4 __attribute__((ext_vector_type(4)));
typedef __bf16 bf16x8 __attribute__((ext_vector_type(8)));
typedef unsigned short u16x4 __attribute__((ext_vector_type(4)));

constexpr int V = 4096;
constexpr int KSPLIT = 4;          // K split factor
constexpr int KSLAB  = V / KSPLIT; // 1024
constexpr int NSLAB  = 3 * KSPLIT; // 12 partial slabs

__device__ __forceinline__ unsigned short f2bf(float f) {
    unsigned int u = __float_as_uint(f);
    u += 0x7FFFu + ((u >> 16) & 1u);           // round-to-nearest-even
    return (unsigned short)(u >> 16);
}
__device__ __forceinline__ float bf2f(unsigned short h) {
    return __uint_as_float(((unsigned int)h) << 16);
}

// ---- kernel 1: z = W @ xv + b  -> bf16 (384 x 4096) --------------------
__global__ __launch_bounds__(256) void k_z(const float* __restrict__ x,
                                           const float* __restrict__ W,
                                           const float* __restrict__ b,
                                           unsigned short* __restrict__ zb) {
    __shared__ float Ws[8 * 128];
    __shared__ float bs[8];
    const int rg = blockIdx.x;
    const int vb = blockIdx.y;
    const int t  = threadIdx.x;
    reinterpret_cast<f32x4*>(Ws)[t] = reinterpret_cast<const f32x4*>(W + rg * 1024)[t];
    if (t < 8) bs[t] = b[rg * 8 + t];
    __syncthreads();
    const int v = vb * 1024 + t * 4;
    f32x4 acc[8] = {};
    #pragma unroll 8
    for (int j = 0; j < 128; ++j) {
        f32x4 xv = *reinterpret_cast<const f32x4*>(x + (size_t)j * V + v);
        #pragma unroll
        for (int q = 0; q < 8; ++q) acc[q] += Ws[q * 128 + j] * xv;
    }
    #pragma unroll
    for (int q = 0; q < 8; ++q) {
        u16x4 u;
        #pragma unroll
        for (int j = 0; j < 4; ++j) u[j] = f2bf(acc[q][j] + bs[q]);
        *reinterpret_cast<u16x4*>(zb + (size_t)(rg * 8 + q) * V + v) = u;
    }
}

// ---- kernel 2: partial[pk] = bf16( z[p] @ A[p][k-slab] ) ---------------
// 768 blocks, 256 thr = 4 waves (2M x 2N wave grid). Tile 128M x 64N, BK=64.
// XCD-contiguous swizzle (nt-minor): neighbors on one XCD cover full A rows.
// Double-buffered LDS; raw lgkm-barrier; issue order z-next -> A-next2 so no
// wait point drains a live prefetch (A stays 2 phases deep, z 1 deep).
__global__ __launch_bounds__(256) void k_gemm(const unsigned short* __restrict__ zb,
                                              const float* __restrict__ A,
                                              unsigned short* __restrict__ partial) {
    // [buf][n(64)][kpair padded to 36] u32 = {bf16 k even, bf16 k odd}
    // bank = (4n + kp)%32: read b128 uniform 8/bank (optimal), write 2-way (free)
    __shared__ unsigned int Bt[2][64][36];

    const int id  = blockIdx.x;
    const int xcd = id & 7;
    const int wg  = xcd * 96 + (id >> 3);      // bijective: 768 = 8 * 96
    const int nt  = wg & 63;                   // minor: same-XCD neighbors adjacent in n
    const int pk  = wg >> 6;                   // 0..11
    const int p   = pk % 3;
    const int kh  = pk / 3;
    const int n0    = nt * 64;
    const int kbase = kh * KSLAB, kend = kbase + KSLAB;

    const int t    = threadIdx.x;
    const int wid  = t >> 6;
    const int lane = t & 63;
    const int lrow = lane & 15;
    const int g    = lane >> 4;
    const int wm   = wid >> 1;                 // 0..1 (M half)
    const int wn   = wid & 1;                  // 0..1 (N half)

    const int r  = t >> 3;                     // kpair 0..31
    const int c  = t & 7;                      // n-octet 0..7
    const int kx = r ^ (c << 2);               // write swizzle (n>>3 == c)

    const float* Ab = A + (size_t)p * V * V + n0 + c * 8;
    const unsigned short* Zb = zb + ((size_t)p * 128 + wm * 64 + lrow) * V + g * 8;

    // read-side fragment coords
    const int nA   = wn * 32 + lrow;
    const int nB   = nA + 16;
    const int sxA  = ((nA >> 3) & 7) << 2;
    const int sxB  = ((nB >> 3) & 7) << 2;
    const int kxA0 = (g * 4) ^ sxA,  kxA1 = (16 + g * 4) ^ sxA;
    const int kxB0 = (g * 4) ^ sxB,  kxB1 = (16 + g * 4) ^ sxB;

    f32x4 acc00 = {}, acc01 = {}, acc10 = {}, acc11 = {};
    f32x4 acc20 = {}, acc21 = {}, acc30 = {}, acc31 = {};
    f32x4 avA0, avA1, avA2, avA3, avB0, avB1, avB2, avB3;
    bf16x8 zA0, zA1, zA2, zA3, zA4, zA5, zA6, zA7;
    bf16x8 zB0, zB1, zB2, zB3, zB4, zB5, zB6, zB7;

#define MFMA(a_, b_, c_) __builtin_amdgcn_mfma_f32_16x16x32_bf16(a_, b_, c_, 0, 0, 0)

#define LOADA(AV, K) { const float* s_ = Ab + (size_t)((K) + 2 * r) * V;                  \
        AV##0 = *reinterpret_cast<const f32x4*>(s_);                                      \
        AV##1 = *reinterpret_cast<const f32x4*>(s_ + 4);                                  \
        AV##2 = *reinterpret_cast<const f32x4*>(s_ + V);                                  \
        AV##3 = *reinterpret_cast<const f32x4*>(s_ + V + 4); }

#define LOADZ(Z, K) { const unsigned short* z_ = Zb + (K);                                \
        Z##0 = *reinterpret_cast<const bf16x8*>(z_);                                      \
        Z##1 = *reinterpret_cast<const bf16x8*>(z_ + 32);                                 \
        Z##2 = *reinterpret_cast<const bf16x8*>(z_ + (size_t)16 * V);                     \
        Z##3 = *reinterpret_cast<const bf16x8*>(z_ + (size_t)16 * V + 32);                \
        Z##4 = *reinterpret_cast<const bf16x8*>(z_ + (size_t)32 * V);                     \
        Z##5 = *reinterpret_cast<const bf16x8*>(z_ + (size_t)32 * V + 32);                \
        Z##6 = *reinterpret_cast<const bf16x8*>(z_ + (size_t)48 * V);                     \
        Z##7 = *reinterpret_cast<const bf16x8*>(z_ + (size_t)48 * V + 32); }

#define PKW(B, J, NOFF, LO, HI) { unsigned int u_;                                        \
        asm("v_cvt_pk_bf16_f32 %0, %1, %2" : "=v"(u_) : "v"(LO), "v"(HI));               \
        Bt[B][c * 8 + (NOFF) + (J)][kx] = u_; }

#define WRITEB(B, AV) {                                                                   \
        PKW(B, 0, 0, AV##0[0], AV##2[0]); PKW(B, 1, 0, AV##0[1], AV##2[1]);               \
        PKW(B, 2, 0, AV##0[2], AV##2[2]); PKW(B, 3, 0, AV##0[3], AV##2[3]);               \
        PKW(B, 0, 4, AV##1[0], AV##3[0]); PKW(B, 1, 4, AV##1[1], AV##3[1]);               \
        PKW(B, 2, 4, AV##1[2], AV##3[2]); PKW(B, 3, 4, AV##1[3], AV##3[3]); }

#define BAR asm volatile("s_waitcnt lgkmcnt(0)\n\ts_barrier" ::: "memory")

#define MFMAP(B, Z) {                                                                     \
        bf16x8 b00 = *reinterpret_cast<const bf16x8*>(&Bt[B][nA][kxA0]);                  \
        bf16x8 b01 = *reinterpret_cast<const bf16x8*>(&Bt[B][nA][kxA1]);                  \
        bf16x8 b10 = *reinterpret_cast<const bf16x8*>(&Bt[B][nB][kxB0]);                  \
        bf16x8 b11 = *reinterpret_cast<const bf16x8*>(&Bt[B][nB][kxB1]);                  \
        acc00 = MFMA(Z##0, b00, acc00); acc01 = MFMA(Z##0, b10, acc01);                   \
        acc00 = MFMA(Z##1, b01, acc00); acc01 = MFMA(Z##1, b11, acc01);                   \
        acc10 = MFMA(Z##2, b00, acc10); acc11 = MFMA(Z##2, b10, acc11);                   \
        acc10 = MFMA(Z##3, b01, acc10); acc11 = MFMA(Z##3, b11, acc11);                   \
        acc20 = MFMA(Z##4, b00, acc20); acc21 = MFMA(Z##4, b10, acc21);                   \
        acc20 = MFMA(Z##5, b01, acc20); acc21 = MFMA(Z##5, b11, acc21);                   \
        acc30 = MFMA(Z##6, b00, acc30); acc31 = MFMA(Z##6, b10, acc31);                   \
        acc30 = MFMA(Z##7, b01, acc30); acc31 = MFMA(Z##7, b11, acc31); }

    // prologue: z(ph0) oldest, then A(ph0), A(ph1)
    LOADZ(zA, kbase);
    LOADA(avA, kbase);
    LOADA(avB, kbase + 64);

    for (int k0 = kbase; k0 < kend; k0 += 128) {
        const int kA2 = (k0 + 128 < kend) ? k0 + 128 : kbase;  // dead-load clamp
        const int kA3 = (k0 + 192 < kend) ? k0 + 192 : kbase;
        // phase even: buf0 (consumes avA, zA)
        WRITEB(0, avA);            // waits avA only (oldest outstanding)
        LOADZ(zB, k0 + 64);        // z first...
        LOADA(avA, kA2);           // ...then A — z-wait won't drain this
        BAR;
        MFMAP(0, zA);
        // phase odd: buf1 (consumes avB, zB)
        WRITEB(1, avB);
        LOADZ(zA, kA2);
        LOADA(avB, kA3);
        BAR;
        MFMAP(1, zB);
    }

    // C/D layout: col = lane&15, row = (lane>>4)*4 + reg   [verified m89/m91]
    unsigned short* Pp = partial + (size_t)pk * 128 * V;
#define STORE(F, AC0, AC1) {                                                              \
        const int row_ = wm * 64 + (F) * 16 + g * 4;                                      \
        const int col_ = n0 + wn * 32 + lrow;                                             \
        _Pragma("unroll")                                                                 \
        for (int rr = 0; rr < 4; ++rr) {                                                  \
            Pp[(size_t)(row_ + rr) * V + col_]      = f2bf(AC0[rr]);                      \
            Pp[(size_t)(row_ + rr) * V + col_ + 16] = f2bf(AC1[rr]);                      \
        } }
    STORE(0, acc00, acc01); STORE(1, acc10, acc11);
    STORE(2, acc20, acc21); STORE(3, acc30, acc31);
#undef MFMA
#undef LOADA
#undef LOADZ
#undef PKW
#undef WRITEB
#undef BAR
#undef MFMAP
#undef STORE
}

// ---- kernel 3: out = relu(x + sum(fifo[:48 slabs]) + sum(12 bf16 partials))
__global__ __launch_bounds__(256) void k_epi(const float* __restrict__ x,
                                             const float* __restrict__ fifo,
                                             const unsigned short* __restrict__ partial,
                                             float* __restrict__ out) {
    const size_t off  = ((size_t)blockIdx.x * 256 + threadIdx.x) * 4;
    const size_t slab = (size_t)128 * V;
    f32x4 s0 = *reinterpret_cast<const f32x4*>(x + off);
    f32x4 s1 = {}, s2 = {}, s3 = {};
    #pragma unroll
    for (int s = 0; s < 48; ++s) {   // fifo[:16] x 3p = first 48 slabs
        f32x4 fv = *reinterpret_cast<const f32x4*>(fifo + (size_t)s * slab + off);
        switch (s & 3) {
            case 0: s0 += fv; break;
            case 1: s1 += fv; break;
            case 2: s2 += fv; break;
            default: s3 += fv; break;
        }
    }
    #pragma unroll
    for (int q = 0; q < NSLAB; ++q) {
        u16x4 pv = *reinterpret_cast<const u16x4*>(partial + (size_t)q * slab + off);
        f32x4 d;
        #pragma unroll
        for (int j = 0; j < 4; ++j) d[j] = bf2f(pv[j]);
        if (q & 1) s1 += d; else s2 += d;
    }
    f32x4 sum = (s0 + s1) + (s2 + s3);
    f32x4 o;
    #pragma unroll
    for (int j = 0; j < 4; ++j) o[j] = fmaxf(sum[j], 0.0f);
    *reinterpret_cast<f32x4*>(out + off) = o;
}

extern "C" void kernel_launch(void* const* d_in, const int* in_sizes, int n_in,
                              void* d_out, int out_size, void* d_ws, size_t ws_size,
                              hipStream_t stream) {
    const float* x    = (const float*)d_in[0];   // (1,128,4096,1)
    const float* A    = (const float*)d_in[1];   // (3,4096,4096)
    const float* fifo = (const float*)d_in[2];   // (17,3,128,4096)
    const float* W    = (const float*)d_in[3];   // (384,128)
    const float* b    = (const float*)d_in[4];   // (384,)
    float* out = (float*)d_out;                  // (1,128,4096) f32

    unsigned short* zb      = (unsigned short*)d_ws;                                    // 3 MB bf16
    unsigned short* partial = (unsigned short*)((char*)d_ws + (size_t)3 * 1024 * 1024); // 12 MB bf16

    k_z   <<<dim3(48, 4), 256, 0, stream>>>(x, W, b, zb);
    k_gemm<<<dim3(768),   256, 0, stream>>>(zb, A, partial);
    k_epi <<<dim3(512),   256, 0, stream>>>(x, fifo, partial, out);
}

// Round 7
// 92.682 us; speedup vs baseline: 1.2881x; 1.2881x over previous
//
#include <hip/hip_runtime.h>

typedef float f32x4 __attribute__((ext_vector_type(4)));
typedef __bf16 bf16x8 __attribute__((ext_vector_type(8)));
typedef unsigned short u16x4 __attribute__((ext_vector_type(4)));
typedef unsigned int u32x4 __attribute__((ext_vector_type(4)));

constexpr int V  = 4096;
constexpr int KS = 5;               // K-split (slabs 832,832,832,832,768)
constexpr int NSLAB = 3 * KS;       // 15 partial slabs

__device__ __forceinline__ unsigned short f2bf(float f) {
    unsigned int u = __float_as_uint(f);
    u += 0x7FFFu + ((u >> 16) & 1u);           // round-to-nearest-even
    return (unsigned short)(u >> 16);
}
__device__ __forceinline__ float bf2f(unsigned short h) {
    return __uint_as_float(((unsigned int)h) << 16);
}

// ---- kernel 1: z = W @ xv + b  -> bf16 (384 x 4096) --------------------
__global__ __launch_bounds__(256) void k_z(const float* __restrict__ x,
                                           const float* __restrict__ W,
                                           const float* __restrict__ b,
                                           unsigned short* __restrict__ zb) {
    __shared__ float Ws[8 * 128];
    __shared__ float bs[8];
    const int rg = blockIdx.x;
    const int vb = blockIdx.y;
    const int t  = threadIdx.x;
    reinterpret_cast<f32x4*>(Ws)[t] = reinterpret_cast<const f32x4*>(W + rg * 1024)[t];
    if (t < 8) bs[t] = b[rg * 8 + t];
    __syncthreads();
    const int v = vb * 1024 + t * 4;
    f32x4 acc[8] = {};
    #pragma unroll 8
    for (int j = 0; j < 128; ++j) {
        f32x4 xv = *reinterpret_cast<const f32x4*>(x + (size_t)j * V + v);
        #pragma unroll
        for (int q = 0; q < 8; ++q) acc[q] += Ws[q * 128 + j] * xv;
    }
    #pragma unroll
    for (int q = 0; q < 8; ++q) {
        u16x4 u;
        #pragma unroll
        for (int j = 0; j < 4; ++j) u[j] = f2bf(acc[q][j] + bs[q]);
        *reinterpret_cast<u16x4*>(zb + (size_t)(rg * 8 + q) * V + v) = u;
    }
}

// ---- kernel 2: partial[p,kh] = bf16( z[p] @ A[p][k-slab] ) -------------
// grid (16 nt, 3 p, 5 kh) = 240 blocks, 256 thr = 4 waves (2M x 2N).
// Tile 128M x 256N, BK=32. Every A-load instruction = 1 KB contiguous:
// thread reads A[k + w*8 + j][n0 + 4l .. +3].
__global__ __launch_bounds__(256, 2) void k_gemm(const unsigned short* __restrict__ zb,
                                                 const float* __restrict__ A,
                                                 unsigned short* __restrict__ partial) {
    // [buf][n(256)][kpair(16) @ pitch 20 u32]  = 40 KB total
    // kp-quad swizzle: stored kp = logical kp XOR (((n>>2)&3)<<2)
    __shared__ unsigned int Bt[2][256][20];

    const int nt = blockIdx.x;     // 0..15
    const int p  = blockIdx.y;     // 0..2
    const int kh = blockIdx.z;     // 0..4
    const int n0    = nt * 256;
    const int kbase = kh * 832;
    const int kend  = (kh == 4) ? 4096 : kbase + 832;

    const int t  = threadIdx.x;
    const int w  = t >> 6;
    const int l  = t & 63;
    const int wm = w >> 1, wn = w & 1;
    const int lrow = l & 15, g = l >> 4;

    // staging read base: rows k + w*8 + j, cols n0 + 4l (1 KB/wave-instr)
    const float* Ab = A + (size_t)p * V * V + (size_t)(w * 8) * V + n0 + l * 4;
    // staging write: n = 4l+q, kp-quad = 4*(w ^ (l&3)); one b128 per q
    const int wswz = (w ^ (l & 3)) << 2;
    // fragment read: n = wn*128 + nn*16 + lrow; swizzled kp-quad:
    const int gp = (g ^ ((lrow >> 2) & 3)) << 2;
    // z fragments: rows m = wm*64 + mt*16 + lrow, k-offset g*8
    const unsigned short* Zb = zb + ((size_t)p * 128 + wm * 64 + lrow) * V + g * 8;

    f32x4 acc[4][8] = {};
    f32x4 arA[8], arB[8];
    bf16x8 zr[4];

#define LOADA(AR, K) { _Pragma("unroll") for (int j = 0; j < 8; ++j) \
        AR[j] = *reinterpret_cast<const f32x4*>(Ab + (size_t)((K) + j) * V); }

#define LOADZ(K) { _Pragma("unroll") for (int mt = 0; mt < 4; ++mt) \
        zr[mt] = *reinterpret_cast<const bf16x8*>(Zb + (size_t)mt * 16 * V + (K)); }

#define WRITEB(B, AR) { _Pragma("unroll") for (int q = 0; q < 4; ++q) { \
        u32x4 pk; \
        asm("v_cvt_pk_bf16_f32 %0, %1, %2" : "=v"(pk[0]) : "v"(AR[0][q]), "v"(AR[1][q])); \
        asm("v_cvt_pk_bf16_f32 %0, %1, %2" : "=v"(pk[1]) : "v"(AR[2][q]), "v"(AR[3][q])); \
        asm("v_cvt_pk_bf16_f32 %0, %1, %2" : "=v"(pk[2]) : "v"(AR[4][q]), "v"(AR[5][q])); \
        asm("v_cvt_pk_bf16_f32 %0, %1, %2" : "=v"(pk[3]) : "v"(AR[6][q]), "v"(AR[7][q])); \
        *reinterpret_cast<u32x4*>(&Bt[B][l * 4 + q][wswz]) = pk; } }

#define BAR asm volatile("s_waitcnt lgkmcnt(0)\n\ts_barrier" ::: "memory")

#define MFMAP(B) { _Pragma("unroll") for (int nn = 0; nn < 8; ++nn) { \
        bf16x8 bf = *reinterpret_cast<const bf16x8*>(&Bt[B][wn * 128 + nn * 16 + lrow][gp]); \
        _Pragma("unroll") for (int mt = 0; mt < 4; ++mt) \
            acc[mt][nn] = __builtin_amdgcn_mfma_f32_16x16x32_bf16(zr[mt], bf, acc[mt][nn], 0, 0, 0); } }

    // prologue
    LOADA(arA, kbase);
    LOADZ(kbase);

    for (int k0 = kbase; k0 < kend; k0 += 64) {
        const int k1 = k0 + 32;
        const int k2 = (k0 + 64 < kend) ? k0 + 64 : kbase;  // dead-load clamp
        // phase 0: consume arA,zr(k0); prefetch arB(k1); reload zr(k1) after use
        WRITEB(0, arA);              // waits only arA's vmcnt
        LOADA(arB, k1);
        BAR;
        MFMAP(0);
        LOADZ(k1);
        // phase 1: consume arB,zr(k1); prefetch arA(k2); reload zr(k2)
        WRITEB(1, arB);
        LOADA(arA, k2);
        BAR;
        MFMAP(1);
        LOADZ(k2);
    }

    // C/D layout: col = lane&15 (n), row = g*4 + reg (m)  [verified r1..r6]
    unsigned short* Pp = partial + (size_t)(p * KS + kh) * 128 * V;
    #pragma unroll
    for (int mt = 0; mt < 4; ++mt)
        #pragma unroll
        for (int nn = 0; nn < 8; ++nn) {
            const size_t base = (size_t)(wm * 64 + mt * 16 + g * 4) * V
                              + n0 + wn * 128 + nn * 16 + lrow;
            #pragma unroll
            for (int r = 0; r < 4; ++r)
                Pp[base + (size_t)r * V] = f2bf(acc[mt][nn][r]);
        }
#undef LOADA
#undef LOADZ
#undef WRITEB
#undef BAR
#undef MFMAP
}

// ---- kernel 3: out = relu(x + sum(fifo[:48 slabs]) + sum(15 bf16 partials))
__global__ __launch_bounds__(256) void k_epi(const float* __restrict__ x,
                                             const float* __restrict__ fifo,
                                             const unsigned short* __restrict__ partial,
                                             float* __restrict__ out) {
    const size_t off  = ((size_t)blockIdx.x * 256 + threadIdx.x) * 4;
    const size_t slab = (size_t)128 * V;
    f32x4 s0 = *reinterpret_cast<const f32x4*>(x + off);
    f32x4 s1 = {}, s2 = {}, s3 = {};
    #pragma unroll
    for (int s = 0; s < 48; ++s) {   // fifo[:16] x 3p = first 48 slabs
        f32x4 fv = *reinterpret_cast<const f32x4*>(fifo + (size_t)s * slab + off);
        switch (s & 3) {
            case 0: s0 += fv; break;
            case 1: s1 += fv; break;
            case 2: s2 += fv; break;
            default: s3 += fv; break;
        }
    }
    #pragma unroll
    for (int q = 0; q < NSLAB; ++q) {
        u16x4 pv = *reinterpret_cast<const u16x4*>(partial + (size_t)q * slab + off);
        f32x4 d;
        #pragma unroll
        for (int j = 0; j < 4; ++j) d[j] = bf2f(pv[j]);
        if (q & 1) s1 += d; else s2 += d;
    }
    f32x4 sum = (s0 + s1) + (s2 + s3);
    f32x4 o;
    #pragma unroll
    for (int j = 0; j < 4; ++j) o[j] = fmaxf(sum[j], 0.0f);
    *reinterpret_cast<f32x4*>(out + off) = o;
}

extern "C" void kernel_launch(void* const* d_in, const int* in_sizes, int n_in,
                              void* d_out, int out_size, void* d_ws, size_t ws_size,
                              hipStream_t stream) {
    const float* x    = (const float*)d_in[0];   // (1,128,4096,1)
    const float* A    = (const float*)d_in[1];   // (3,4096,4096)
    const float* fifo = (const float*)d_in[2];   // (17,3,128,4096)
    const float* W    = (const float*)d_in[3];   // (384,128)
    const float* b    = (const float*)d_in[4];   // (384,)
    float* out = (float*)d_out;                  // (1,128,4096) f32

    unsigned short* zb      = (unsigned short*)d_ws;                                    // 3 MB bf16
    unsigned short* partial = (unsigned short*)((char*)d_ws + (size_t)3 * 1024 * 1024); // 15 MB bf16

    k_z   <<<dim3(48, 4),    256, 0, stream>>>(x, W, b, zb);
    k_gemm<<<dim3(16, 3, KS), 256, 0, stream>>>(zb, A, partial);
    k_epi <<<dim3(512),      256, 0, stream>>>(x, fifo, partial, out);
}